// Round 1
// baseline (1885.876 us; speedup 1.0000x reference)
//
#include <hip/hip_runtime.h>
#include <hip/hip_bf16.h>
#include <math.h>

#define NRAYS 4096
#define NS    256
#define KK    12
#define GS    160
#define G3    (160*160*160)
#define WID   128

__device__ __forceinline__ float softplusf(float x) {
    // jax.nn.softplus: max(x,0) + log1p(exp(-|x|))
    return fmaxf(x, 0.f) + log1pf(expf(-fabsf(x)));
}
__device__ __forceinline__ float sigmoidf(float x) {
    return 1.f / (1.f + expf(-x));
}

__global__ __launch_bounds__(256, 1)
void voxgo_fwd(const float* __restrict__ rays_o, const float* __restrict__ rays_d,
               const float* __restrict__ dgrid, const float* __restrict__ sgrid,
               const float* __restrict__ k0g,
               const float* __restrict__ w0, const float* __restrict__ b0,
               const float* __restrict__ w1, const float* __restrict__ b1,
               const float* __restrict__ w2, const float* __restrict__ b2,
               const float* __restrict__ eps_den, const float* __restrict__ eps_rgb,
               float* __restrict__ out)
{
    const float BGL   = 0.2f;
    const float XMIN  = -1.2f;
    const float SCALE = 159.0f / 2.4f;
    const float ACT_SHIFT = -9.2102403672f;   // log(1/(1-1e-4)-1)
    const float STEP  = 0.0075f;              // 0.5 * 2.4/160
    const float NEART = 0.1f;

    __shared__ float buf[256 * 129];   // per-thread row: feat[39] then h1[128]
    __shared__ float scanw[4][KK];
    __shared__ float red[4][3];

    const int r    = blockIdx.x;
    const int s    = threadIdx.x;
    const int lane = s & 63;
    const int wv   = s >> 6;

    // ---- ray / sample point ----
    float dx = rays_d[r*3+0], dy = rays_d[r*3+1], dz = rays_d[r*3+2];
    float inv = rsqrtf(dx*dx + dy*dy + dz*dz);
    dx *= inv; dy *= inv; dz *= inv;
    float t  = NEART + STEP * (float)s;
    float px = rays_o[r*3+0] + dx*t;
    float py = rays_o[r*3+1] + dy*t;
    float pz = rays_o[r*3+2] + dz*t;
    float an = fmaxf(fabsf(px), fmaxf(fabsf(py), fabsf(pz)));
    if (an > 1.0f) {
        float sc = (1.0f + BGL - BGL/an) / an;
        px *= sc; py *= sc; pz *= sc;
    }
    // ---- trilinear setup ----
    float ux = (px - XMIN)*SCALE, uy = (py - XMIN)*SCALE, uz = (pz - XMIN)*SCALE;
    int ix = min(max((int)floorf(ux), 0), GS-2);
    int iy = min(max((int)floorf(uy), 0), GS-2);
    int iz = min(max((int)floorf(uz), 0), GS-2);
    float fx = ux-(float)ix, fy = uy-(float)iy, fz = uz-(float)iz;
    float gx = 1.f-fx, gy = 1.f-fy, gz = 1.f-fz;
    const int oY = GS, oX = GS*GS;
    const int o000 = (ix*GS + iy)*GS + iz;
    float c00 = gx*gy, c01 = gx*fy, c10 = fx*gy, c11 = fx*fy;

    auto tri = [&](const float* __restrict__ g) -> float {
        float v00 = g[o000]*gz       + g[o000+1]*fz;
        float v01 = g[o000+oY]*gz    + g[o000+oY+1]*fz;
        float v10 = g[o000+oX]*gz    + g[o000+oX+1]*fz;
        float v11 = g[o000+oX+oY]*gz + g[o000+oX+oY+1]*fz;
        return v00*c00 + v01*c01 + v10*c10 + v11*c11;
    };

    float raw_den = tri(dgrid);
    float raw_std = tri(sgrid);
    float k0v[KK];
#pragma unroll
    for (int c = 0; c < KK; ++c) k0v[c] = tri(k0g + c*G3);

    // ---- stochastic alpha, K=12 ----
    float stdv = softplusf(raw_std);
    float alpha[KK], incl[KK];
#pragma unroll
    for (int k = 0; k < KK; ++k) {
        float den = raw_den + stdv * eps_den[k];
        float sp  = softplusf(den + ACT_SHIFT);
        float e   = expf(-sp * 0.5f);
        alpha[k]  = 1.f - e;
        incl[k]   = e + 1e-10f;          // q = 1 - alpha + 1e-10
    }
    // ---- exclusive cumprod over samples: wave shfl scan + cross-wave fixup ----
#pragma unroll
    for (int d = 1; d < 64; d <<= 1) {
#pragma unroll
        for (int k = 0; k < KK; ++k) {
            float v = __shfl_up(incl[k], d, 64);
            if (lane >= d) incl[k] *= v;
        }
    }
    if (lane == 63) {
#pragma unroll
        for (int k = 0; k < KK; ++k) scanw[wv][k] = incl[k];
    }
    __syncthreads();
    float wk[KK];
#pragma unroll
    for (int k = 0; k < KK; ++k) {
        float pref = 1.f;
        for (int pw = 0; pw < wv; ++pw) pref *= scanw[pw][k];
        float ex = __shfl_up(incl[k], 1, 64);
        if (lane == 0) ex = 1.f;
        wk[k] = alpha[k] * (pref * ex);
    }

    // ---- features -> LDS row ----
    float* frow = &buf[s * 129];
#pragma unroll
    for (int c = 0; c < KK; ++c) frow[c] = k0v[c];
    frow[12] = dx; frow[13] = dy; frow[14] = dz;
    {
        float vdv[3] = {dx, dy, dz};
#pragma unroll
        for (int a = 0; a < 3; ++a) {
#pragma unroll
            for (int p = 0; p < 4; ++p) {
                float arg = vdv[a] * (float)(1 << p);
                float sv, cv;
                __sincosf(arg, &sv, &cv);
                frow[15 + a*4 + p] = sv;
                frow[27 + a*4 + p] = cv;
            }
        }
    }

    // ---- layer 1: 39 -> 128 ----
    float h[WID];
#pragma unroll
    for (int j = 0; j < WID; ++j) h[j] = b0[j];
    for (int i = 0; i < 39; ++i) {
        float fv = frow[i];
        const float* wr = w0 + i*WID;
#pragma unroll
        for (int j = 0; j < WID; ++j) h[j] = fmaf(fv, wr[j], h[j]);
    }
#pragma unroll
    for (int j = 0; j < WID; ++j) frow[j] = fmaxf(h[j], 0.f);  // relu(h1) -> LDS

    // ---- layer 2: 128 -> 128 ----
    float h2[WID];
#pragma unroll
    for (int j = 0; j < WID; ++j) h2[j] = b1[j];
    for (int i = 0; i < WID; ++i) {
        float fv = frow[i];
        const float* wr = w1 + i*WID;
#pragma unroll
        for (int j = 0; j < WID; ++j) h2[j] = fmaf(fv, wr[j], h2[j]);
    }

    // ---- layer 3: 128 -> 6 (fused relu) ----
    float o6[6];
#pragma unroll
    for (int c = 0; c < 6; ++c) o6[c] = b2[c];
#pragma unroll
    for (int j = 0; j < WID; ++j) {
        float hv = fmaxf(h2[j], 0.f);
#pragma unroll
        for (int c = 0; c < 6; ++c) o6[c] = fmaf(hv, w2[j*6+c], o6[c]);
    }

    // ---- stochastic rgb + march ----
    // out[r,c] = 1 + (1/12) * sum_{s,k} w[s,k] * (sigmoid(mean_c + std_c*eps_rgb[k,c]) - 1)
    float m0 = o6[0], m1 = o6[1], m2 = o6[2];
    float s0 = softplusf(o6[3]), s1 = softplusf(o6[4]), s2 = softplusf(o6[5]);
    float p0 = 0.f, p1 = 0.f, p2 = 0.f;
#pragma unroll
    for (int k = 0; k < KK; ++k) {
        float w = wk[k];
        p0 += w * (sigmoidf(m0 + s0*eps_rgb[k*3+0]) - 1.f);
        p1 += w * (sigmoidf(m1 + s1*eps_rgb[k*3+1]) - 1.f);
        p2 += w * (sigmoidf(m2 + s2*eps_rgb[k*3+2]) - 1.f);
    }
    // ---- block reduction of 3 floats ----
#pragma unroll
    for (int d = 32; d > 0; d >>= 1) {
        p0 += __shfl_down(p0, d, 64);
        p1 += __shfl_down(p1, d, 64);
        p2 += __shfl_down(p2, d, 64);
    }
    if (lane == 0) { red[wv][0] = p0; red[wv][1] = p1; red[wv][2] = p2; }
    __syncthreads();
    if (s == 0) {
        float a0 = red[0][0] + red[1][0] + red[2][0] + red[3][0];
        float a1 = red[0][1] + red[1][1] + red[2][1] + red[3][1];
        float a2 = red[0][2] + red[1][2] + red[2][2] + red[3][2];
        out[r*3+0] = 1.f + a0 * (1.f/12.f);
        out[r*3+1] = 1.f + a1 * (1.f/12.f);
        out[r*3+2] = 1.f + a2 * (1.f/12.f);
    }
}

extern "C" void kernel_launch(void* const* d_in, const int* in_sizes, int n_in,
                              void* d_out, int out_size, void* d_ws, size_t ws_size,
                              hipStream_t stream) {
    const float* rays_o  = (const float*)d_in[0];
    const float* rays_d  = (const float*)d_in[1];
    const float* dgrid   = (const float*)d_in[2];
    const float* sgrid   = (const float*)d_in[3];
    const float* k0g     = (const float*)d_in[4];
    const float* w0      = (const float*)d_in[5];
    const float* b0      = (const float*)d_in[6];
    const float* w1      = (const float*)d_in[7];
    const float* b1      = (const float*)d_in[8];
    const float* w2      = (const float*)d_in[9];
    const float* b2      = (const float*)d_in[10];
    const float* eps_den = (const float*)d_in[11];
    const float* eps_rgb = (const float*)d_in[12];
    float* out = (float*)d_out;

    voxgo_fwd<<<NRAYS, 256, 0, stream>>>(rays_o, rays_d, dgrid, sgrid, k0g,
                                         w0, b0, w1, b1, w2, b2,
                                         eps_den, eps_rgb, out);
}

// Round 2
// 285.198 us; speedup vs baseline: 6.6125x; 6.6125x over previous
//
#include <hip/hip_runtime.h>
#include <hip/hip_bf16.h>
#include <math.h>

#define NRAYS 4096
#define KK    12
#define GS    160
#define G3    (GS*GS*GS)

typedef __bf16 bf16x8 __attribute__((ext_vector_type(8)));
typedef float  f32x4  __attribute__((ext_vector_type(4)));

// d_ws layout (bf16 elements):
//  w0T [128 n][64 k]   @ 0      (k>=39 zero-padded)
//  w1T [128 n][128 k]  @ 8192
//  w2T [16 n][128 k]   @ 24576  (n>=6 zero-padded)
#define W0T_OFF 0
#define W1T_OFF 8192
#define W2T_OFF 24576

__device__ __forceinline__ float softplusf(float x) {
    return fmaxf(x, 0.f) + log1pf(expf(-fabsf(x)));
}
__device__ __forceinline__ float sigmoidf(float x) {
    return 1.f / (1.f + expf(-x));
}
__device__ __forceinline__ unsigned pk2(float a, float b) {
    unsigned short x = __builtin_bit_cast(unsigned short, (__bf16)a);
    unsigned short y = __builtin_bit_cast(unsigned short, (__bf16)b);
    return (unsigned)x | ((unsigned)y << 16);
}
// swizzled byte offset into the activation buffer: row stride 256B,
// XOR chunk swizzle to kill the 16-way bank conflict on stride-256 reads
__device__ __forceinline__ int xoff(int m, int kb) {
    return m * 256 + (kb ^ ((m & 7) << 4));
}

__global__ void prep_weights(const float* __restrict__ w0, const float* __restrict__ w1,
                             const float* __restrict__ w2, __bf16* __restrict__ ws)
{
    int i = blockIdx.x * 256 + threadIdx.x;
    if (i < 8192) {                       // w0T [n][k<64]
        int n = i >> 6, k = i & 63;
        ws[W0T_OFF + i] = (__bf16)((k < 39) ? w0[k * 128 + n] : 0.f);
    } else if (i < 24576) {               // w1T [n][k<128]
        int j = i - 8192;
        int n = j >> 7, k = j & 127;
        ws[W1T_OFF + j] = (__bf16)(w1[k * 128 + n]);
    } else if (i < 26624) {               // w2T [n<16][k<128]
        int j = i - 24576;
        int n = j >> 7, k = j & 127;
        ws[W2T_OFF + j] = (__bf16)((n < 6) ? w2[k * 6 + n] : 0.f);
    }
}

__global__ __launch_bounds__(256, 2)
void voxgo_fwd(const float* __restrict__ rays_o, const float* __restrict__ rays_d,
               const float* __restrict__ dgrid, const float* __restrict__ sgrid,
               const float* __restrict__ k0g,
               const float* __restrict__ b0, const float* __restrict__ b1,
               const float* __restrict__ b2,
               const float* __restrict__ eps_den, const float* __restrict__ eps_rgb,
               const __bf16* __restrict__ wsb,
               float* __restrict__ out)
{
    const float BGL   = 0.2f;
    const float XMIN  = -1.2f;
    const float SCALE = 159.0f / 2.4f;
    const float ACT_SHIFT = -9.2102403672f;
    const float STEP  = 0.0075f;
    const float NEART = 0.1f;

    __shared__ uint4 xbuf4[4096];          // 64 KB activation buffer
    __shared__ float scanw[4][KK];
    __shared__ float red[4][3];
    char* xb = (char*)xbuf4;

    const int r    = blockIdx.x;
    const int s    = threadIdx.x;
    const int lane = s & 63;
    const int wv   = s >> 6;

    // ================= phase 1: point, gather, alpha, scan =================
    float dx = rays_d[r*3+0], dy = rays_d[r*3+1], dz = rays_d[r*3+2];
    float inv = rsqrtf(dx*dx + dy*dy + dz*dz);
    dx *= inv; dy *= inv; dz *= inv;
    float t  = NEART + STEP * (float)s;
    float px = rays_o[r*3+0] + dx*t;
    float py = rays_o[r*3+1] + dy*t;
    float pz = rays_o[r*3+2] + dz*t;
    float an = fmaxf(fabsf(px), fmaxf(fabsf(py), fabsf(pz)));
    if (an > 1.0f) {
        float sc = (1.0f + BGL - BGL/an) / an;
        px *= sc; py *= sc; pz *= sc;
    }
    float ux = (px - XMIN)*SCALE, uy = (py - XMIN)*SCALE, uz = (pz - XMIN)*SCALE;
    int ix = min(max((int)floorf(ux), 0), GS-2);
    int iy = min(max((int)floorf(uy), 0), GS-2);
    int iz = min(max((int)floorf(uz), 0), GS-2);
    float fx = ux-(float)ix, fy = uy-(float)iy, fz = uz-(float)iz;
    float gx = 1.f-fx, gy = 1.f-fy, gz = 1.f-fz;
    const int oY = GS, oX = GS*GS;
    const int o000 = (ix*GS + iy)*GS + iz;
    float c00 = gx*gy, c01 = gx*fy, c10 = fx*gy, c11 = fx*fy;

    auto tri = [&](const float* __restrict__ g) -> float {
        float v00 = g[o000]*gz       + g[o000+1]*fz;
        float v01 = g[o000+oY]*gz    + g[o000+oY+1]*fz;
        float v10 = g[o000+oX]*gz    + g[o000+oX+1]*fz;
        float v11 = g[o000+oX+oY]*gz + g[o000+oX+oY+1]*fz;
        return v00*c00 + v01*c01 + v10*c10 + v11*c11;
    };

    float raw_den = tri(dgrid);
    float raw_std = tri(sgrid);
    float k0v[KK];
#pragma unroll
    for (int c = 0; c < KK; ++c) k0v[c] = tri(k0g + c*G3);

    float stdv = softplusf(raw_std);
    float alpha[KK], incl[KK];
#pragma unroll
    for (int k = 0; k < KK; ++k) {
        float den = raw_den + stdv * eps_den[k];
        float sp  = softplusf(den + ACT_SHIFT);
        float e   = expf(-sp * 0.5f);
        alpha[k]  = 1.f - e;
        incl[k]   = e + 1e-10f;
    }
#pragma unroll
    for (int d = 1; d < 64; d <<= 1) {
#pragma unroll
        for (int k = 0; k < KK; ++k) {
            float v = __shfl_up(incl[k], d, 64);
            if (lane >= d) incl[k] *= v;
        }
    }
    if (lane == 63) {
#pragma unroll
        for (int k = 0; k < KK; ++k) scanw[wv][k] = incl[k];
    }
    __syncthreads();
    float wk[KK];
#pragma unroll
    for (int k = 0; k < KK; ++k) {
        float pref = 1.f;
        for (int pw = 0; pw < wv; ++pw) pref *= scanw[pw][k];
        float ex = __shfl_up(incl[k], 1, 64);
        if (lane == 0) ex = 1.f;
        wk[k] = alpha[k] * (pref * ex);
    }

    // ================= phase 2: features -> LDS (bf16, swizzled) ==========
    float fv[64];
#pragma unroll
    for (int c = 0; c < KK; ++c) fv[c] = k0v[c];
    fv[12] = dx; fv[13] = dy; fv[14] = dz;
    {
        float vdv[3] = {dx, dy, dz};
#pragma unroll
        for (int a = 0; a < 3; ++a) {
#pragma unroll
            for (int p = 0; p < 4; ++p) {
                float arg = vdv[a] * (float)(1 << p);
                float sv, cv;
                __sincosf(arg, &sv, &cv);
                fv[15 + a*4 + p] = sv;
                fv[27 + a*4 + p] = cv;
            }
        }
    }
#pragma unroll
    for (int c = 39; c < 64; ++c) fv[c] = 0.f;

#pragma unroll
    for (int c = 0; c < 8; ++c) {
        uint4 v;
        v.x = pk2(fv[c*8+0], fv[c*8+1]);
        v.y = pk2(fv[c*8+2], fv[c*8+3]);
        v.z = pk2(fv[c*8+4], fv[c*8+5]);
        v.w = pk2(fv[c*8+6], fv[c*8+7]);
        *(uint4*)(xb + xoff(s, c*16)) = v;
    }
    __syncthreads();

    // ================= phase 3: MFMA MLP ===================================
    // convention: D[n][m] = sum_k W[k][n] * X[m][k]; A = W^T tile (global),
    // B = X rows (LDS). Frags: A lane l: row=l&15 (n), k=(l>>4)*8+j;
    // B lane l: col=l&15 (m), k=(l>>4)*8+j; D lane l: row=(l>>4)*4+q (n), col=l&15 (m).
    const int lm = lane & 15, lk = lane >> 4;
    const int Mb = wv * 64;

    f32x4 acc[4][8];
    // ---- L1: feat(64) -> 128
    {
        const __bf16* w0t = wsb + W0T_OFF;
#pragma unroll
        for (int nt = 0; nt < 8; ++nt) {
            int n0 = nt*16 + lk*4;
            f32x4 bi = { b0[n0], b0[n0+1], b0[n0+2], b0[n0+3] };
#pragma unroll
            for (int mt = 0; mt < 4; ++mt) acc[mt][nt] = bi;
        }
#pragma unroll
        for (int ks = 0; ks < 2; ++ks) {
            bf16x8 bfr[4];
#pragma unroll
            for (int mt = 0; mt < 4; ++mt)
                bfr[mt] = *(const bf16x8*)(xb + xoff(Mb + mt*16 + lm, ks*64 + lk*16));
#pragma unroll
            for (int nt = 0; nt < 8; ++nt) {
                bf16x8 af = *(const bf16x8*)(w0t + (nt*16 + lm)*64 + ks*32 + lk*8);
#pragma unroll
                for (int mt = 0; mt < 4; ++mt)
                    acc[mt][nt] = __builtin_amdgcn_mfma_f32_16x16x32_bf16(af, bfr[mt], acc[mt][nt], 0, 0, 0);
            }
        }
    }
    __syncthreads();
    // relu -> h1 to LDS
#pragma unroll
    for (int mt = 0; mt < 4; ++mt) {
        int mr = Mb + mt*16 + lm;
#pragma unroll
        for (int nt = 0; nt < 8; ++nt) {
            f32x4 v = acc[mt][nt];
            uint2 p;
            p.x = pk2(fmaxf(v.x, 0.f), fmaxf(v.y, 0.f));
            p.y = pk2(fmaxf(v.z, 0.f), fmaxf(v.w, 0.f));
            *(uint2*)(xb + xoff(mr, nt*32 + lk*8)) = p;
        }
    }
    __syncthreads();
    // ---- L2: 128 -> 128
    {
        const __bf16* w1t = wsb + W1T_OFF;
#pragma unroll
        for (int nt = 0; nt < 8; ++nt) {
            int n0 = nt*16 + lk*4;
            f32x4 bi = { b1[n0], b1[n0+1], b1[n0+2], b1[n0+3] };
#pragma unroll
            for (int mt = 0; mt < 4; ++mt) acc[mt][nt] = bi;
        }
#pragma unroll
        for (int ks = 0; ks < 4; ++ks) {
            bf16x8 bfr[4];
#pragma unroll
            for (int mt = 0; mt < 4; ++mt)
                bfr[mt] = *(const bf16x8*)(xb + xoff(Mb + mt*16 + lm, ks*64 + lk*16));
#pragma unroll
            for (int nt = 0; nt < 8; ++nt) {
                bf16x8 af = *(const bf16x8*)(w1t + (nt*16 + lm)*128 + ks*32 + lk*8);
#pragma unroll
                for (int mt = 0; mt < 4; ++mt)
                    acc[mt][nt] = __builtin_amdgcn_mfma_f32_16x16x32_bf16(af, bfr[mt], acc[mt][nt], 0, 0, 0);
            }
        }
    }
    __syncthreads();
    // relu -> h2 to LDS
#pragma unroll
    for (int mt = 0; mt < 4; ++mt) {
        int mr = Mb + mt*16 + lm;
#pragma unroll
        for (int nt = 0; nt < 8; ++nt) {
            f32x4 v = acc[mt][nt];
            uint2 p;
            p.x = pk2(fmaxf(v.x, 0.f), fmaxf(v.y, 0.f));
            p.y = pk2(fmaxf(v.z, 0.f), fmaxf(v.w, 0.f));
            *(uint2*)(xb + xoff(mr, nt*32 + lk*8)) = p;
        }
    }
    __syncthreads();
    // ---- L3: 128 -> 16 (cols 0..5 valid)
    f32x4 a3[4];
    {
        const __bf16* w2t = wsb + W2T_OFF;
        f32x4 bi;
        bi.x = (lk*4+0 < 6) ? b2[lk*4+0] : 0.f;
        bi.y = (lk*4+1 < 6) ? b2[lk*4+1] : 0.f;
        bi.z = (lk*4+2 < 6) ? b2[lk*4+2] : 0.f;
        bi.w = (lk*4+3 < 6) ? b2[lk*4+3] : 0.f;
#pragma unroll
        for (int mt = 0; mt < 4; ++mt) a3[mt] = bi;
#pragma unroll
        for (int ks = 0; ks < 4; ++ks) {
            bf16x8 af = *(const bf16x8*)(w2t + lm*128 + ks*32 + lk*8);
#pragma unroll
            for (int mt = 0; mt < 4; ++mt) {
                bf16x8 bfr = *(const bf16x8*)(xb + xoff(Mb + mt*16 + lm, ks*64 + lk*16));
                a3[mt] = __builtin_amdgcn_mfma_f32_16x16x32_bf16(af, bfr, a3[mt], 0, 0, 0);
            }
        }
    }
    __syncthreads();   // all waves done reading h2 before overlay write
    float* outf = (float*)xb;  // overlay: [256][20] f32
#pragma unroll
    for (int mt = 0; mt < 4; ++mt)
        *(f32x4*)&outf[(Mb + mt*16 + lm)*20 + lk*4] = a3[mt];
    __syncthreads();

    // ================= phase 4: stochastic rgb + march ====================
    float o6[6];
#pragma unroll
    for (int c = 0; c < 6; ++c) o6[c] = outf[s*20 + c];

    float m0 = o6[0], m1 = o6[1], m2 = o6[2];
    float s0 = softplusf(o6[3]), s1 = softplusf(o6[4]), s2 = softplusf(o6[5]);
    float p0 = 0.f, p1 = 0.f, p2 = 0.f;
#pragma unroll
    for (int k = 0; k < KK; ++k) {
        float w = wk[k];
        p0 += w * (sigmoidf(m0 + s0*eps_rgb[k*3+0]) - 1.f);
        p1 += w * (sigmoidf(m1 + s1*eps_rgb[k*3+1]) - 1.f);
        p2 += w * (sigmoidf(m2 + s2*eps_rgb[k*3+2]) - 1.f);
    }
#pragma unroll
    for (int d = 32; d > 0; d >>= 1) {
        p0 += __shfl_down(p0, d, 64);
        p1 += __shfl_down(p1, d, 64);
        p2 += __shfl_down(p2, d, 64);
    }
    if (lane == 0) { red[wv][0] = p0; red[wv][1] = p1; red[wv][2] = p2; }
    __syncthreads();
    if (s == 0) {
        float a0 = red[0][0] + red[1][0] + red[2][0] + red[3][0];
        float a1 = red[0][1] + red[1][1] + red[2][1] + red[3][1];
        float a2 = red[0][2] + red[1][2] + red[2][2] + red[3][2];
        out[r*3+0] = 1.f + a0 * (1.f/12.f);
        out[r*3+1] = 1.f + a1 * (1.f/12.f);
        out[r*3+2] = 1.f + a2 * (1.f/12.f);
    }
}

extern "C" void kernel_launch(void* const* d_in, const int* in_sizes, int n_in,
                              void* d_out, int out_size, void* d_ws, size_t ws_size,
                              hipStream_t stream) {
    const float* rays_o  = (const float*)d_in[0];
    const float* rays_d  = (const float*)d_in[1];
    const float* dgrid   = (const float*)d_in[2];
    const float* sgrid   = (const float*)d_in[3];
    const float* k0g     = (const float*)d_in[4];
    const float* w0      = (const float*)d_in[5];
    const float* b0      = (const float*)d_in[6];
    const float* w1      = (const float*)d_in[7];
    const float* b1      = (const float*)d_in[8];
    const float* w2      = (const float*)d_in[9];
    const float* b2      = (const float*)d_in[10];
    const float* eps_den = (const float*)d_in[11];
    const float* eps_rgb = (const float*)d_in[12];
    float* out = (float*)d_out;
    __bf16* wsb = (__bf16*)d_ws;

    prep_weights<<<104, 256, 0, stream>>>(w0, w1, w2, wsb);
    voxgo_fwd<<<NRAYS, 256, 0, stream>>>(rays_o, rays_d, dgrid, sgrid, k0g,
                                         b0, b1, b2, eps_den, eps_rgb, wsb, out);
}